// Round 6
// baseline (2101.333 us; speedup 1.0000x reference)
//
#include <hip/hip_runtime.h>
#include <hip/hip_bf16.h>
#include <stdint.h>

// GraphSAGE layer, N=16384, F_IN=F_OUT=256.
// out = (adj@ (x@W1))/deg + x@W2 + bias
//   K0: WT[n][k] (bf16)  = transpose of [W1|W2]
//   K1: yT[n][m] (bf16)  = (x@W1)^T ;  z[m][n] (f32) = x@W2 + bias
//   K2 v6: NO-LDS, NO-BARRIER direct-fragment GEMM. Each lane loads its MFMA
//          fragments straight from global (A: adj ints -> bf16 pack in regs;
//          B: yT already K-contiguous = B-frag layout), depth-1 register
//          prefetch. No __syncthreads -> no vmcnt(0) drains, no phase-lock.
//          Cross-wave operand duplication (A x4, B x2) is L1/L2-served.
//   K3: out = (p0+p1)/(d0+d1) + z

typedef short bf16x8 __attribute__((ext_vector_type(8)));
typedef float f32x4  __attribute__((ext_vector_type(4)));

__device__ __forceinline__ uint32_t pack_bf16_rne(float lo, float hi) {
    uint32_t ul = __float_as_uint(lo);
    uint32_t uh = __float_as_uint(hi);
    ul = (ul + 0x7fffu + ((ul >> 16) & 1u)) >> 16;
    uh = (uh + 0x7fffu + ((uh >> 16) & 1u)) >> 16;
    return ul | (uh << 16);
}

// ---------------- K0: transpose weight [512,256] f32 -> WT [512(n)][256(k)] bf16
__global__ __launch_bounds__(256) void k_transpose_w(const float* __restrict__ w,
                                                     uint16_t* __restrict__ wt) {
    int idx = blockIdx.x * 256 + threadIdx.x;   // 0..131071
    int n = idx >> 8;
    int k = idx & 255;
    int row = (n < 256) ? k : (256 + k);
    int col = (n < 256) ? n : (n - 256);
    uint32_t u = __float_as_uint(w[row * 256 + col]);
    u = (u + 0x7fffu + ((u >> 16) & 1u)) >> 16;
    wt[idx] = (uint16_t)u;
}

// ---------------- K1: small GEMM  [16384,256] @ [256,512] -> yT (cols 0..255) / z (cols 256..511)
__global__ __launch_bounds__(256) void k_small_gemm(const float* __restrict__ x,
                                                    const uint16_t* __restrict__ wt,
                                                    const float* __restrict__ bias,
                                                    uint16_t* __restrict__ yT,
                                                    float* __restrict__ z) {
    __shared__ uint16_t As[128 * 32];  // [m][k] bf16
    __shared__ uint16_t Bs[128 * 32];  // [n][k] bf16

    const int t  = threadIdx.x;
    const int ct = blockIdx.x;        // 0..3
    const int rt = blockIdx.y;        // 0..127
    const int m0 = rt * 128;
    const int n0 = ct * 128;

    const int lane = t & 63, w = t >> 6;
    const int wr = w >> 1, wc = w & 1;
    const int l15 = lane & 15, quad = lane >> 4;

    f32x4 acc[4][4] = {};

    float4 a_reg[4];
    uint4  b_reg[2];

#pragma unroll
    for (int i = 0; i < 4; ++i) {
        int f4 = t + 256 * i, row = f4 >> 3, c4 = f4 & 7;
        a_reg[i] = *(const float4*)(x + (m0 + row) * 256 + c4 * 4);
    }
#pragma unroll
    for (int i = 0; i < 2; ++i) {
        int u4 = t + 256 * i, n_l = u4 >> 2, part = u4 & 3;
        b_reg[i] = *(const uint4*)(wt + (n0 + n_l) * 256 + part * 8);
    }

    for (int kk = 0; kk < 8; ++kk) {
        __syncthreads();
#pragma unroll
        for (int i = 0; i < 4; ++i) {
            int f4 = t + 256 * i, row = f4 >> 3, c4 = f4 & 7;
            uint2 p;
            p.x = pack_bf16_rne(a_reg[i].x, a_reg[i].y);
            p.y = pack_bf16_rne(a_reg[i].z, a_reg[i].w);
            *(uint2*)(As + row * 32 + c4 * 4) = p;
        }
#pragma unroll
        for (int i = 0; i < 2; ++i) {
            int u4 = t + 256 * i, n_l = u4 >> 2, part = u4 & 3;
            *(uint4*)(Bs + n_l * 32 + part * 8) = b_reg[i];
        }
        if (kk < 7) {
            int k0 = (kk + 1) * 32;
#pragma unroll
            for (int i = 0; i < 4; ++i) {
                int f4 = t + 256 * i, row = f4 >> 3, c4 = f4 & 7;
                a_reg[i] = *(const float4*)(x + (m0 + row) * 256 + k0 + c4 * 4);
            }
#pragma unroll
            for (int i = 0; i < 2; ++i) {
                int u4 = t + 256 * i, n_l = u4 >> 2, part = u4 & 3;
                b_reg[i] = *(const uint4*)(wt + (n0 + n_l) * 256 + k0 + part * 8);
            }
        }
        __syncthreads();

        bf16x8 a_frag[4], b_frag[4];
#pragma unroll
        for (int fr = 0; fr < 4; ++fr)
            a_frag[fr] = *(const bf16x8*)(As + (wr * 64 + fr * 16 + l15) * 32 + quad * 8);
#pragma unroll
        for (int fc = 0; fc < 4; ++fc)
            b_frag[fc] = *(const bf16x8*)(Bs + (wc * 64 + fc * 16 + l15) * 32 + quad * 8);
#pragma unroll
        for (int fr = 0; fr < 4; ++fr)
#pragma unroll
            for (int fc = 0; fc < 4; ++fc)
                acc[fr][fc] = __builtin_amdgcn_mfma_f32_16x16x32_bf16(
                    a_frag[fr], b_frag[fc], acc[fr][fc], 0, 0, 0);
    }

    if (ct < 2) {
#pragma unroll
        for (int fr = 0; fr < 4; ++fr) {
            int m_base = m0 + wr * 64 + fr * 16 + quad * 4;
#pragma unroll
            for (int fc = 0; fc < 4; ++fc) {
                int n_g = n0 + wc * 64 + fc * 16 + l15;   // 0..255
                uint2 pp;
                pp.x = pack_bf16_rne(acc[fr][fc][0], acc[fr][fc][1]);
                pp.y = pack_bf16_rne(acc[fr][fc][2], acc[fr][fc][3]);
                *(uint2*)(yT + (size_t)n_g * 16384 + m_base) = pp;
            }
        }
    } else {
#pragma unroll
        for (int fr = 0; fr < 4; ++fr) {
            int m_base = m0 + wr * 64 + fr * 16 + quad * 4;
#pragma unroll
            for (int fc = 0; fc < 4; ++fc) {
                int n_g = (n0 - 256) + wc * 64 + fc * 16 + l15;  // 0..255
                float bv = bias[n_g];
#pragma unroll
                for (int r = 0; r < 4; ++r)
                    z[(size_t)(m_base + r) * 256 + n_g] = acc[fr][fc][r] + bv;
            }
        }
    }
}

// ---------------- K2 v6: partial[ky] = adj[:, ky-half] @ y[ky-half, :]
// grid (256 row-tiles, 2 k-halves), 512 threads (8 waves; wave = 32x64),
// BK=32, 256 iters. NO LDS, NO BARRIERS: per-lane direct fragment loads with
// depth-1 register prefetch. A-frag layout: lane reads adj[row=wr*32+fr*16+l15]
// [k0 + quad*8 .. +8) as 2x int4, packed to bf16x8 in registers. B-frag:
// yT[n=wc*64+fc*16+l15][k0 + quad*8 ..] is already the B fragment (16B load).
#define KITER 256
__global__ __launch_bounds__(512, 4) void k_big_gemm(const int* __restrict__ adj,
                                                     const uint16_t* __restrict__ yT,
                                                     float* __restrict__ part,
                                                     int* __restrict__ degw) {
    const int t = threadIdx.x;
    const int m0 = blockIdx.x * 64;
    const int ky = blockIdx.y;                     // k-half
    const int kbase = ky * 8192;
    const int lane = t & 63, w = t >> 6;
    const int wr = w >> 2, wc = w & 3;             // wave: 2 row frags, 4 col frags
    const int l15 = lane & 15, quad = lane >> 4;

    f32x4 acc[2][4] = {};

    // A pointers: this lane's two a-frag rows, k-chunk quad*8
    const int* pa0 = adj + (size_t)(m0 + wr * 32 + l15) * 16384 + kbase + quad * 8;
    const int* pa1 = pa0 + (size_t)16 * 16384;
    // B pointers: four b-frag rows of yT
    const uint16_t* pb0 = yT + (size_t)(wc * 64 +  0 + l15) * 16384 + kbase + quad * 8;
    const uint16_t* pb1 = pb0 + (size_t)16 * 16384;
    const uint16_t* pb2 = pb0 + (size_t)32 * 16384;
    const uint16_t* pb3 = pb0 + (size_t)48 * 16384;

    // ---- prefetch k-step 0
    int4 n0lo = *(const int4*)pa0, n0hi = *(const int4*)(pa0 + 4);
    int4 n1lo = *(const int4*)pa1, n1hi = *(const int4*)(pa1 + 4);
    uint4 nb0 = *(const uint4*)pb0, nb1 = *(const uint4*)pb1;
    uint4 nb2 = *(const uint4*)pb2, nb3 = *(const uint4*)pb3;
    pa0 += 32; pa1 += 32; pb0 += 32; pb1 += 32; pb2 += 32; pb3 += 32;

    int deg0 = 0, deg1 = 0;
    const bool is_deg = (wc == 0);                 // count each adj element once

    for (int kk = 0; kk < KITER; ++kk) {
        // rotate next -> current (SSA renames, no real moves after unroll)
        int4 c0lo = n0lo, c0hi = n0hi, c1lo = n1lo, c1hi = n1hi;
        uint4 cb0 = nb0, cb1 = nb1, cb2 = nb2, cb3 = nb3;

        // issue next-iter loads; they stay in flight through this iter's MFMA
        if (kk < KITER - 1) {
            n0lo = *(const int4*)pa0; n0hi = *(const int4*)(pa0 + 4);
            n1lo = *(const int4*)pa1; n1hi = *(const int4*)(pa1 + 4);
            nb0 = *(const uint4*)pb0; nb1 = *(const uint4*)pb1;
            nb2 = *(const uint4*)pb2; nb3 = *(const uint4*)pb3;
            pa0 += 32; pa1 += 32; pb0 += 32; pb1 += 32; pb2 += 32; pb3 += 32;
        }

        // convert current A ints -> bf16 fragments ((a|b<<16)*0x3F80 pack)
        uint4 u0, u1;
        u0.x = (uint32_t)(c0lo.x | (c0lo.y << 16)) * 0x3F80u;
        u0.y = (uint32_t)(c0lo.z | (c0lo.w << 16)) * 0x3F80u;
        u0.z = (uint32_t)(c0hi.x | (c0hi.y << 16)) * 0x3F80u;
        u0.w = (uint32_t)(c0hi.z | (c0hi.w << 16)) * 0x3F80u;
        u1.x = (uint32_t)(c1lo.x | (c1lo.y << 16)) * 0x3F80u;
        u1.y = (uint32_t)(c1lo.z | (c1lo.w << 16)) * 0x3F80u;
        u1.z = (uint32_t)(c1hi.x | (c1hi.y << 16)) * 0x3F80u;
        u1.w = (uint32_t)(c1hi.z | (c1hi.w << 16)) * 0x3F80u;

        if (is_deg) {
            deg0 += c0lo.x + c0lo.y + c0lo.z + c0lo.w + c0hi.x + c0hi.y + c0hi.z + c0hi.w;
            deg1 += c1lo.x + c1lo.y + c1lo.z + c1lo.w + c1hi.x + c1hi.y + c1hi.z + c1hi.w;
        }

        bf16x8 af0 = *(bf16x8*)&u0;
        bf16x8 af1 = *(bf16x8*)&u1;
        bf16x8 bf0 = *(bf16x8*)&cb0;
        bf16x8 bf1 = *(bf16x8*)&cb1;
        bf16x8 bf2 = *(bf16x8*)&cb2;
        bf16x8 bf3 = *(bf16x8*)&cb3;

        acc[0][0] = __builtin_amdgcn_mfma_f32_16x16x32_bf16(af0, bf0, acc[0][0], 0, 0, 0);
        acc[0][1] = __builtin_amdgcn_mfma_f32_16x16x32_bf16(af0, bf1, acc[0][1], 0, 0, 0);
        acc[0][2] = __builtin_amdgcn_mfma_f32_16x16x32_bf16(af0, bf2, acc[0][2], 0, 0, 0);
        acc[0][3] = __builtin_amdgcn_mfma_f32_16x16x32_bf16(af0, bf3, acc[0][3], 0, 0, 0);
        acc[1][0] = __builtin_amdgcn_mfma_f32_16x16x32_bf16(af1, bf0, acc[1][0], 0, 0, 0);
        acc[1][1] = __builtin_amdgcn_mfma_f32_16x16x32_bf16(af1, bf1, acc[1][1], 0, 0, 0);
        acc[1][2] = __builtin_amdgcn_mfma_f32_16x16x32_bf16(af1, bf2, acc[1][2], 0, 0, 0);
        acc[1][3] = __builtin_amdgcn_mfma_f32_16x16x32_bf16(af1, bf3, acc[1][3], 0, 0, 0);
    }

    // deg reduce: lanes {l15, l15+16, l15+32, l15+48} hold k-oct partials of
    // the same row; butterfly them down to lanes 0..15
    if (is_deg) {
        deg0 += __shfl_down(deg0, 16); deg0 += __shfl_down(deg0, 32);
        deg1 += __shfl_down(deg1, 16); deg1 += __shfl_down(deg1, 32);
        if (lane < 16) {
            degw[ky * 16384 + m0 + wr * 32 + l15]      = deg0;
            degw[ky * 16384 + m0 + wr * 32 + 16 + l15] = deg1;
        }
    }

    // partial C (C/D layout: col=lane&15, row=quad*4+reg)
    float* pc = part + (size_t)ky * 16384 * 256;
#pragma unroll
    for (int fr = 0; fr < 2; ++fr) {
#pragma unroll
        for (int r = 0; r < 4; ++r) {
            int m_l = wr * 32 + fr * 16 + quad * 4 + r;
            size_t mrow = (size_t)(m0 + m_l) * 256;
#pragma unroll
            for (int fc = 0; fc < 4; ++fc) {
                int n_g = wc * 64 + fc * 16 + l15;
                pc[mrow + n_g] = acc[fr][fc][r];
            }
        }
    }
}

// ---------------- K3: out = (p0+p1)/(d0+d1) + z
__global__ __launch_bounds__(256) void k_reduce(const float* __restrict__ part,
                                                const int* __restrict__ degw,
                                                const float* __restrict__ z,
                                                float* __restrict__ out) {
    int i4 = blockIdx.x * 256 + threadIdx.x;       // float4 index, 64 per row
    int m = i4 >> 6;
    float4 p0 = ((const float4*)part)[i4];
    float4 p1 = ((const float4*)part)[i4 + 16384 * 64];
    float4 zz = ((const float4*)z)[i4];
    float inv = 1.0f / (float)(degw[m] + degw[16384 + m]);
    float4 o;
    o.x = (p0.x + p1.x) * inv + zz.x;
    o.y = (p0.y + p1.y) * inv + zz.y;
    o.z = (p0.z + p1.z) * inv + zz.z;
    o.w = (p0.w + p1.w) * inv + zz.w;
    ((float4*)out)[i4] = o;
}

extern "C" void kernel_launch(void* const* d_in, const int* in_sizes, int n_in,
                              void* d_out, int out_size, void* d_ws, size_t ws_size,
                              hipStream_t stream) {
    const float* x      = (const float*)d_in[0];
    const int*   adj    = (const int*)d_in[1];
    const float* weight = (const float*)d_in[2];
    const float* bias   = (const float*)d_in[3];
    float* out = (float*)d_out;

    // ws: WT 256KB | yT 8MB | z 16MB | part 33.5MB | degw 128KB
    uint16_t* wt   = (uint16_t*)d_ws;
    uint16_t* yT   = (uint16_t*)((char*)d_ws + 262144);
    float*    z    = (float*)((char*)d_ws + 262144 + 8388608);
    float*    partb= (float*)((char*)d_ws + 262144 + 8388608 + 16777216);
    int*      degw = (int*)((char*)d_ws + 262144 + 8388608 + 16777216 + 33554432);

    k_transpose_w<<<512, 256, 0, stream>>>(weight, wt);
    k_small_gemm<<<dim3(4, 128), 256, 0, stream>>>(x, wt, bias, yT, z);
    k_big_gemm<<<dim3(256, 2), 512, 0, stream>>>(adj, yT, partb, degw);
    k_reduce<<<4096, 256, 0, stream>>>(partb, degw, z, out);
}

// Round 7
// 1500.697 us; speedup vs baseline: 1.4002x; 1.4002x over previous
//
#include <hip/hip_runtime.h>
#include <hip/hip_bf16.h>
#include <stdint.h>

// GraphSAGE layer, N=16384, F_IN=F_OUT=256.
// out = (adj@ (x@W1))/deg + x@W2 + bias
//   K0: WT[n][k] (bf16)  = transpose of [W1|W2]
//   K1: yT[n][m] (bf16)  = (x@W1)^T ;  z[m][n] (f32) = x@W2 + bias
//   K2 v7: v5's coalesced staging (split-K 2, 8 waves of 32x64, BK=32) but
//          TRI-BUFFERED with a RAW s_barrier (inline asm, lgkmcnt(0) only —
//          never vmcnt(0)). Stage kk+2 issued each iter; manual
//          s_waitcnt vmcnt(3) guarantees stage kk+1 landed. Distinct
//          __shared__ arrays per stage so the compiler's LDS-DMA alias
//          tracking doesn't insert conservative waits before the ds_reads.
//   K3: out = (p0+p1)/(d0+d1) + z

typedef short bf16x8 __attribute__((ext_vector_type(8)));
typedef float f32x4  __attribute__((ext_vector_type(4)));

__device__ __forceinline__ uint32_t pack_bf16_rne(float lo, float hi) {
    uint32_t ul = __float_as_uint(lo);
    uint32_t uh = __float_as_uint(hi);
    ul = (ul + 0x7fffu + ((ul >> 16) & 1u)) >> 16;
    uh = (uh + 0x7fffu + ((uh >> 16) & 1u)) >> 16;
    return ul | (uh << 16);
}

__device__ __forceinline__ void gload_lds16(const void* g, void* l) {
    __builtin_amdgcn_global_load_lds(
        (__attribute__((address_space(1))) void*)g,
        (__attribute__((address_space(3))) void*)l, 16, 0, 0);
}

// ---------------- K0: transpose weight [512,256] f32 -> WT [512(n)][256(k)] bf16
__global__ __launch_bounds__(256) void k_transpose_w(const float* __restrict__ w,
                                                     uint16_t* __restrict__ wt) {
    int idx = blockIdx.x * 256 + threadIdx.x;   // 0..131071
    int n = idx >> 8;
    int k = idx & 255;
    int row = (n < 256) ? k : (256 + k);
    int col = (n < 256) ? n : (n - 256);
    uint32_t u = __float_as_uint(w[row * 256 + col]);
    u = (u + 0x7fffu + ((u >> 16) & 1u)) >> 16;
    wt[idx] = (uint16_t)u;
}

// ---------------- K1: small GEMM  [16384,256] @ [256,512] -> yT (cols 0..255) / z (cols 256..511)
__global__ __launch_bounds__(256) void k_small_gemm(const float* __restrict__ x,
                                                    const uint16_t* __restrict__ wt,
                                                    const float* __restrict__ bias,
                                                    uint16_t* __restrict__ yT,
                                                    float* __restrict__ z) {
    __shared__ uint16_t As[128 * 32];  // [m][k] bf16
    __shared__ uint16_t Bs[128 * 32];  // [n][k] bf16

    const int t  = threadIdx.x;
    const int ct = blockIdx.x;        // 0..3
    const int rt = blockIdx.y;        // 0..127
    const int m0 = rt * 128;
    const int n0 = ct * 128;

    const int lane = t & 63, w = t >> 6;
    const int wr = w >> 1, wc = w & 1;
    const int l15 = lane & 15, quad = lane >> 4;

    f32x4 acc[4][4] = {};

    float4 a_reg[4];
    uint4  b_reg[2];

#pragma unroll
    for (int i = 0; i < 4; ++i) {
        int f4 = t + 256 * i, row = f4 >> 3, c4 = f4 & 7;
        a_reg[i] = *(const float4*)(x + (m0 + row) * 256 + c4 * 4);
    }
#pragma unroll
    for (int i = 0; i < 2; ++i) {
        int u4 = t + 256 * i, n_l = u4 >> 2, part = u4 & 3;
        b_reg[i] = *(const uint4*)(wt + (n0 + n_l) * 256 + part * 8);
    }

    for (int kk = 0; kk < 8; ++kk) {
        __syncthreads();
#pragma unroll
        for (int i = 0; i < 4; ++i) {
            int f4 = t + 256 * i, row = f4 >> 3, c4 = f4 & 7;
            uint2 p;
            p.x = pack_bf16_rne(a_reg[i].x, a_reg[i].y);
            p.y = pack_bf16_rne(a_reg[i].z, a_reg[i].w);
            *(uint2*)(As + row * 32 + c4 * 4) = p;
        }
#pragma unroll
        for (int i = 0; i < 2; ++i) {
            int u4 = t + 256 * i, n_l = u4 >> 2, part = u4 & 3;
            *(uint4*)(Bs + n_l * 32 + part * 8) = b_reg[i];
        }
        if (kk < 7) {
            int k0 = (kk + 1) * 32;
#pragma unroll
            for (int i = 0; i < 4; ++i) {
                int f4 = t + 256 * i, row = f4 >> 3, c4 = f4 & 7;
                a_reg[i] = *(const float4*)(x + (m0 + row) * 256 + k0 + c4 * 4);
            }
#pragma unroll
            for (int i = 0; i < 2; ++i) {
                int u4 = t + 256 * i, n_l = u4 >> 2, part = u4 & 3;
                b_reg[i] = *(const uint4*)(wt + (n0 + n_l) * 256 + k0 + part * 8);
            }
        }
        __syncthreads();

        bf16x8 a_frag[4], b_frag[4];
#pragma unroll
        for (int fr = 0; fr < 4; ++fr)
            a_frag[fr] = *(const bf16x8*)(As + (wr * 64 + fr * 16 + l15) * 32 + quad * 8);
#pragma unroll
        for (int fc = 0; fc < 4; ++fc)
            b_frag[fc] = *(const bf16x8*)(Bs + (wc * 64 + fc * 16 + l15) * 32 + quad * 8);
#pragma unroll
        for (int fr = 0; fr < 4; ++fr)
#pragma unroll
            for (int fc = 0; fc < 4; ++fc)
                acc[fr][fc] = __builtin_amdgcn_mfma_f32_16x16x32_bf16(
                    a_frag[fr], b_frag[fc], acc[fr][fc], 0, 0, 0);
    }

    if (ct < 2) {
#pragma unroll
        for (int fr = 0; fr < 4; ++fr) {
            int m_base = m0 + wr * 64 + fr * 16 + quad * 4;
#pragma unroll
            for (int fc = 0; fc < 4; ++fc) {
                int n_g = n0 + wc * 64 + fc * 16 + l15;   // 0..255
                uint2 pp;
                pp.x = pack_bf16_rne(acc[fr][fc][0], acc[fr][fc][1]);
                pp.y = pack_bf16_rne(acc[fr][fc][2], acc[fr][fc][3]);
                *(uint2*)(yT + (size_t)n_g * 16384 + m_base) = pp;
            }
        }
    } else {
#pragma unroll
        for (int fr = 0; fr < 4; ++fr) {
            int m_base = m0 + wr * 64 + fr * 16 + quad * 4;
#pragma unroll
            for (int fc = 0; fc < 4; ++fc) {
                int n_g = (n0 - 256) + wc * 64 + fc * 16 + l15;  // 0..255
                float bv = bias[n_g];
#pragma unroll
                for (int r = 0; r < 4; ++r)
                    z[(size_t)(m_base + r) * 256 + n_g] = acc[fr][fc][r] + bv;
            }
        }
    }
}

// ---------------- K2 v7: partial[ky] = adj[:, ky-half] @ y[ky-half, :]
// grid (256 row-tiles, 2 k-halves), 512 threads (8 waves; wave = 32x64),
// BK=32, 256 iters. Tri-buffered LDS (distinct __shared__ arrays), raw
// s_barrier (lgkmcnt(0) only), manual vmcnt(3) stage handshake.
#define A_STRIDE 40                 // 64 rows x 40 halfwords (80B row, conflict-free)
#define A_SZ (64 * A_STRIDE)        // 2560 hw = 5120 B
#define B_SZ (256 * 32)             // 8192 hw = 16384 B, XOR-swizzled
#define KITER 256

// One pipeline step. CONS/PACK/ISSUE are compile-time buffer ids (kk%3 etc).
#define BIG_STEP(CONS, PACK, ISSUE, KK)                                         \
  do {                                                                          \
    int4 aNew = aB;                                                             \
    if ((KK) < KITER - 2) {                                                     \
      aNew = pa4[0]; pa4 += 8;                                                  \
      gload_lds16(pbg0, Bs##ISSUE + b_lb0); pbg0 += 32;                         \
      gload_lds16(pbg1, Bs##ISSUE + b_lb1); pbg1 += 32;                         \
    }                                                                           \
    /* stage KK+1 (issued last step) is everything older than the 3 newest */   \
    asm volatile("s_waitcnt vmcnt(3)" ::: "memory");                            \
    if ((KK) < KITER - 1) {                                                     \
      degp += aB.x + aB.y + aB.z + aB.w;                                        \
      uint2 pv;                                                                 \
      pv.x = (uint32_t)(aB.x | (aB.y << 16)) * 0x3F80u;                         \
      pv.y = (uint32_t)(aB.z | (aB.w << 16)) * 0x3F80u;                         \
      *(uint2*)&As##PACK[a_lds] = pv;                                           \
      aB = aNew;                                                                \
    }                                                                           \
    {                                                                           \
      bf16x8 af[2], bfr[4];                                                     \
      _Pragma("unroll") for (int fr = 0; fr < 2; ++fr) {                        \
        int row = wr * 32 + fr * 16 + l15;                                      \
        af[fr] = *(const bf16x8*)(As##CONS + row * A_STRIDE + quad * 8);        \
      }                                                                         \
      _Pragma("unroll") for (int fc = 0; fc < 4; ++fc) {                        \
        int n = wc * 64 + fc * 16 + l15;                                        \
        int cs = quad ^ ((n >> 1) & 3);                                         \
        bfr[fc] = *(const bf16x8*)(Bs##CONS + n * 32 + cs * 8);                 \
      }                                                                         \
      _Pragma("unroll") for (int fr = 0; fr < 2; ++fr)                          \
        _Pragma("unroll") for (int fc = 0; fc < 4; ++fc)                        \
          acc[fr][fc] = __builtin_amdgcn_mfma_f32_16x16x32_bf16(                \
              af[fr], bfr[fc], acc[fr][fc], 0, 0, 0);                           \
    }                                                                           \
    /* raw barrier: LDS drained, vmem left in flight */                         \
    asm volatile("s_waitcnt lgkmcnt(0)\n\ts_barrier" ::: "memory");             \
  } while (0)

__global__ __launch_bounds__(512, 4) void k_big_gemm(const int* __restrict__ adj,
                                                     const uint16_t* __restrict__ yT,
                                                     float* __restrict__ part,
                                                     int* __restrict__ degw) {
    __shared__ uint16_t As0[A_SZ], As1[A_SZ], As2[A_SZ];
    __shared__ uint16_t Bs0[B_SZ], Bs1[B_SZ], Bs2[B_SZ];

    const int t = threadIdx.x;
    const int m0 = blockIdx.x * 64;
    const int ky = blockIdx.y;                     // k-half
    const int kbase = ky * 8192;
    const int lane = t & 63, w = t >> 6;
    const int wr = w >> 2, wc = w & 3;             // wave: 2 row frags, 4 col frags
    const int l15 = lane & 15, quad = lane >> 4;

    f32x4 acc[2][4] = {};

    // A staging: 64 rows x 32 ints / iter = 512 int4, one per thread
    const int a_n = t >> 3, a_c4 = t & 7;
    const int4* pa4 = (const int4*)(adj + (size_t)(m0 + a_n) * 16384 + kbase) + a_c4;
    const int a_lds = a_n * A_STRIDE + a_c4 * 4;

    // B staging: 256 rows x 32 bf16 / iter = 1024 16B slots, 2 gload_lds/thread
    const uint16_t *pbg0, *pbg1;
    int b_lb0, b_lb1;
    {
        int base0 = (w * 2 + 0) * 64, base1 = (w * 2 + 1) * 64;
        int s0 = base0 + lane, s1 = base1 + lane;
        int bn0 = s0 >> 2, bn1 = s1 >> 2;
        int bc0 = (s0 & 3) ^ ((bn0 >> 1) & 3);
        int bc1 = (s1 & 3) ^ ((bn1 >> 1) & 3);
        pbg0 = yT + (size_t)bn0 * 16384 + kbase + bc0 * 8;
        pbg1 = yT + (size_t)bn1 * 16384 + kbase + bc1 * 8;
        b_lb0 = base0 * 8;
        b_lb1 = base1 * 8;
    }

    // ---- prologue: stage 0 -> buf0, stage 1 -> buf1
    gload_lds16(pbg0, Bs0 + b_lb0); pbg0 += 32;
    gload_lds16(pbg1, Bs0 + b_lb1); pbg1 += 32;
    int4 a0 = pa4[0];
    gload_lds16(pbg0, Bs1 + b_lb0); pbg0 += 32;
    gload_lds16(pbg1, Bs1 + b_lb1); pbg1 += 32;
    int4 aB = pa4[8];
    pa4 += 16;
    // 6 vmem outstanding; wait till <=2 -> stage-0 B (first 2 gloads) complete
    asm volatile("s_waitcnt vmcnt(2)" ::: "memory");
    int degp = a0.x + a0.y + a0.z + a0.w;
    {
        uint2 pv;
        pv.x = (uint32_t)(a0.x | (a0.y << 16)) * 0x3F80u;
        pv.y = (uint32_t)(a0.z | (a0.w << 16)) * 0x3F80u;
        *(uint2*)&As0[a_lds] = pv;
    }
    asm volatile("s_waitcnt lgkmcnt(0)\n\ts_barrier" ::: "memory");

    // ---- main loop: 85 triples (kk = 0..254), then the tail step kk = 255
    for (int kk = 0; kk < KITER - 1; kk += 3) {
        BIG_STEP(0, 1, 2, kk);
        BIG_STEP(1, 2, 0, kk + 1);
        BIG_STEP(2, 0, 1, kk + 2);
    }
    BIG_STEP(0, 1, 2, KITER - 1);   // 255 % 3 == 0

    // partial deg: row a_n owned by 8 consecutive lanes
    degp += __shfl_down(degp, 4);
    degp += __shfl_down(degp, 2);
    degp += __shfl_down(degp, 1);
    if ((t & 7) == 0) degw[ky * 16384 + m0 + a_n] = degp;

    // partial C (C/D layout: col=lane&15, row=quad*4+reg)
    float* pc = part + (size_t)ky * 16384 * 256;
#pragma unroll
    for (int fr = 0; fr < 2; ++fr) {
#pragma unroll
        for (int r = 0; r < 4; ++r) {
            int m_l = wr * 32 + fr * 16 + quad * 4 + r;
            size_t mrow = (size_t)(m0 + m_l) * 256;
#pragma unroll
            for (int fc = 0; fc < 4; ++fc) {
                int n_g = wc * 64 + fc * 16 + l15;
                pc[mrow + n_g] = acc[fr][fc][r];
            }
        }
    }
}

// ---------------- K3: out = (p0+p1)/(d0+d1) + z
__global__ __launch_bounds__(256) void k_reduce(const float* __restrict__ part,
                                                const int* __restrict__ degw,
                                                const float* __restrict__ z,
                                                float* __restrict__ out) {
    int i4 = blockIdx.x * 256 + threadIdx.x;       // float4 index, 64 per row
    int m = i4 >> 6;
    float4 p0 = ((const float4*)part)[i4];
    float4 p1 = ((const float4*)part)[i4 + 16384 * 64];
    float4 zz = ((const float4*)z)[i4];
    float inv = 1.0f / (float)(degw[m] + degw[16384 + m]);
    float4 o;
    o.x = (p0.x + p1.x) * inv + zz.x;
    o.y = (p0.y + p1.y) * inv + zz.y;
    o.z = (p0.z + p1.z) * inv + zz.z;
    o.w = (p0.w + p1.w) * inv + zz.w;
    ((float4*)out)[i4] = o;
}

extern "C" void kernel_launch(void* const* d_in, const int* in_sizes, int n_in,
                              void* d_out, int out_size, void* d_ws, size_t ws_size,
                              hipStream_t stream) {
    const float* x      = (const float*)d_in[0];
    const int*   adj    = (const int*)d_in[1];
    const float* weight = (const float*)d_in[2];
    const float* bias   = (const float*)d_in[3];
    float* out = (float*)d_out;

    // ws: WT 256KB | yT 8MB | z 16MB | part 33.5MB | degw 128KB
    uint16_t* wt   = (uint16_t*)d_ws;
    uint16_t* yT   = (uint16_t*)((char*)d_ws + 262144);
    float*    z    = (float*)((char*)d_ws + 262144 + 8388608);
    float*    partb= (float*)((char*)d_ws + 262144 + 8388608 + 16777216);
    int*      degw = (int*)((char*)d_ws + 262144 + 8388608 + 16777216 + 33554432);

    k_transpose_w<<<512, 256, 0, stream>>>(weight, wt);
    k_small_gemm<<<dim3(4, 128), 256, 0, stream>>>(x, wt, bias, yT, z);
    k_big_gemm<<<dim3(256, 2), 512, 0, stream>>>(adj, yT, partb, degw);
    k_reduce<<<4096, 256, 0, stream>>>(partb, degw, z, out);
}